// Round 10
// baseline (169.700 us; speedup 1.0000x reference)
//
#include <hip/hip_runtime.h>
#include <hip/hip_fp16.h>

// GCN 3-layer, N=100000 nodes, E=800000 edges, f32.
// out = A_hat @ (relu(A_hat @ (relu((A_hat @ x) @ W1 + b1)) @ W2 + b2) @ W3) + b3
// A_hat = D^-1/2 (A + I) D^-1/2, weighted, deg over dst.
//
// R6: MFMA l1. R7/R9: LDS counting bucket sort. R8: edge-parallel agg kernels.
// R10: atomic-free build, 5 dispatches:
//   k_coarse: LDS sort -> contiguous per-block stage dump + cnt/ofs tables
//             (no global atomics, no k_zero, no per-bucket run copies)
//   k_fine:   per-bucket block scans its 125 table entries, binary-search
//             position -> stage read -> LDS slotting (sorted array gone)
//   k_l1:     agg1 fused in (agg phase -> LDS -> MFMA phase), 64 nodes/block

constexpr int N = 100000;
constexpr int E = 800000;
constexpr int NBKT = 391;    // buckets of 256 nodes
constexpr int GC = 125;      // coarse blocks; 125 * 6400 = E exactly
constexpr int CHUNK = 6400;  // 25 full 256-thread iterations
constexpr int CAP = 64;      // payload row capacity (self+Poisson(8) max << 64)

static inline int cdiv(int a, int b) { return (a + b - 1) / b; }

typedef __attribute__((ext_vector_type(8))) _Float16 f16x8;
typedef __attribute__((ext_vector_type(4))) float f32x4;

// coarse: block-local LDS counting sort by dst>>8; outputs per-(block,bucket)
// counts/offsets + contiguous record dump. record = {src | (dst&255)<<17, w}
__global__ __launch_bounds__(256) void k_coarse(const int* __restrict__ src,
                                                const int* __restrict__ dst,
                                                const float* __restrict__ w,
                                                int* __restrict__ cnt2d,
                                                int* __restrict__ lofs2d,
                                                int2* __restrict__ stage) {
    __shared__ int  hist[NBKT];
    __shared__ int  scan[512];
    __shared__ int2 recs[CHUNK];    // 51.2 KB
    int t = threadIdx.x;
    for (int i = t; i < NBKT; i += 256) hist[i] = 0;
    __syncthreads();
    int begin = blockIdx.x * CHUNK;
    int packed[25];                 // (rank<<17) | (bkt<<8) | dlo
#pragma unroll
    for (int i = 0; i < 25; i++) {
        int d = dst[begin + i * 256 + t];
        int b = d >> 8;
        int rank = atomicAdd(&hist[b], 1);     // LDS atomic only
        packed[i] = (rank << 17) | (b << 8) | (d & 255);
    }
    __syncthreads();
    // exclusive scan of hist via two 256-wide H-S scans
    int v0 = hist[t];
    int v1 = (256 + t < NBKT) ? hist[256 + t] : 0;
    scan[t] = v0; scan[256 + t] = v1;
    __syncthreads();
    for (int off = 1; off < 256; off <<= 1) {
        int u0 = (t >= off) ? scan[t - off] : 0;
        int u1 = (t >= off) ? scan[256 + t - off] : 0;
        __syncthreads();
        scan[t] += u0; scan[256 + t] += u1;
        __syncthreads();
    }
    int tot0 = scan[255];
    scan[t] -= v0;                       // inclusive -> exclusive
    scan[256 + t] += tot0 - v1;
    __syncthreads();
    // tables (plain coalesced stores — replaces global-atomic reservation)
    for (int i = t; i < NBKT; i += 256) {
        cnt2d[blockIdx.x * NBKT + i] = hist[i];
        lofs2d[blockIdx.x * NBKT + i] = scan[i];
    }
    // sort records into LDS (bucket-major)
#pragma unroll
    for (int i = 0; i < 25; i++) {
        int e = begin + i * 256 + t;
        int pk = packed[i];
        int b = (pk >> 8) & 511, rank = pk >> 17, dlo = pk & 255;
        recs[scan[b] + rank] = make_int2(src[e] | (dlo << 17), __float_as_int(w[e]));
    }
    __syncthreads();
    // contiguous dump — fully coalesced streaming store
    for (int i = t; i < CHUNK; i += 256)
        stage[(size_t)blockIdx.x * CHUNK + i] = recs[i];
}

// fine: one block per bucket (512 thr). Gathers its 125 stage segments via
// LDS prefix + binary search; LDS slotting; emits payload rows (slot 0 =
// self-loop {n,1.0}, padded to x8 with {0,0}), cursor, dis.
__global__ __launch_bounds__(512) void k_fine(const int* __restrict__ cnt2d,
                                              const int* __restrict__ lofs2d,
                                              const int2* __restrict__ stage,
                                              int2* __restrict__ payload,
                                              int* __restrict__ cursor,
                                              float* __restrict__ dis) {
    __shared__ int   ncnt[256];
    __shared__ float nwsum[256];
    __shared__ int   sofs[GC];
    __shared__ int   sbase[GC + 1];
    __shared__ int   stmp[128];
    int t = threadIdx.x, b = blockIdx.x;
    if (t < 256) { ncnt[t] = 1; nwsum[t] = 1.0f; }   // slot 0 = self-loop
    int cval = 0;
    if (t < GC) { cval = cnt2d[t * NBKT + b]; sofs[t] = lofs2d[t * NBKT + b]; }
    if (t < 128) stmp[t] = (t < GC) ? cval : 0;
    __syncthreads();
    for (int off = 1; off < 128; off <<= 1) {        // inclusive H-S scan
        int u = (t < 128 && t >= off) ? stmp[t - off] : 0;
        __syncthreads();
        if (t < 128) stmp[t] += u;
        __syncthreads();
    }
    if (t < GC) sbase[t] = stmp[t] - cval;           // exclusive
    if (t == GC - 1) sbase[GC] = stmp[t];            // total
    __syncthreads();
    int total = sbase[GC];
    for (int i = t; i < total; i += 512) {
        int lo = 0, hi = GC - 1;                     // last gc with sbase<=i
        while (lo < hi) { int mid = (lo + hi + 1) >> 1;
                          if (sbase[mid] <= i) lo = mid; else hi = mid - 1; }
        int2 r = stage[(size_t)lo * CHUNK + sofs[lo] + (i - sbase[lo])];
        int s = r.x & 0x1FFFF, dlo = r.x >> 17;
        int pos = atomicAdd(&ncnt[dlo], 1);
        atomicAdd(&nwsum[dlo], __int_as_float(r.y));
        if (pos < CAP)
            payload[(size_t)(b * 256 + dlo) * CAP + pos] = make_int2(s, r.y);
    }
    __syncthreads();
    int n = b * 256 + t;
    if (t < 256 && n < N) {
        int c = ncnt[t]; if (c > CAP) c = CAP;
        int2* row = payload + (size_t)n * CAP;
        row[0] = make_int2(n, __float_as_int(1.0f));   // self-loop entry
        int cpad = (c + 7) & ~7;
        for (int e = c; e < cpad; e++) row[e] = make_int2(0, 0);
        cursor[n] = c;
        dis[n] = rsqrtf(nwsum[t]);
    }
}

// ---- fused layer-1: per-node aggregation (norm once/edge, written back to
// payload.y) -> LDS -> relu(.@W1+b1)@W2 via MFMA, fp16 out. 64 nodes/block.
constexpr int HROW = 136;  // f16 units per node row in h1 LDS tile
__global__ __launch_bounds__(256) void k_l1(const float* __restrict__ x,
                                            const float* __restrict__ dis,
                                            const int* __restrict__ cursor,
                                            int2* __restrict__ payload,
                                            const float* __restrict__ W1,
                                            const float* __restrict__ b1,
                                            const float* __restrict__ W2,
                                            __half* __restrict__ y2h) {
    __shared__ float    shagg[4][64];          // per-wave 16 nodes x 4 feats
    __shared__ _Float16 h1lds[4][16 * HROW];   // 4 waves x 4352 B
    int t = threadIdx.x, wave = t >> 6, lane = t & 63;
    // ---- aggregation phase: 4 nodes x 4 slots x 4 feats, 4 chunks ----
    int nsub = lane >> 4, slot = (lane >> 2) & 3, feat = lane & 3;
    int base_n = blockIdx.x * 64 + wave * 16;
#pragma unroll
    for (int chunk = 0; chunk < 4; chunk++) {
        int n = base_n + chunk * 4 + nsub;
        float acc = 0.f;
        if (n < N) {
            float di = dis[n];
            int cnt = cursor[n];
            int2* row = payload + (size_t)n * CAP;
            int iters = (cnt + 3) >> 2;
            for (int it = 0; it < iters; it++) {
                int e = it * 4 + slot;
                int2 p = row[e];
                float nm = dis[p.x] * __int_as_float(p.y) * di;  // pad: 0
                acc = fmaf(nm, x[p.x * 4 + feat], acc);
                if (feat == 0) row[e].y = __float_as_int(nm);    // norm writeback
            }
        }
        acc += __shfl_xor(acc, 4);
        acc += __shfl_xor(acc, 8);
        if (slot == 0) shagg[wave][(chunk * 4 + nsub) * 4 + feat] = acc;
    }
    // shagg[wave] is wave-private: no block barrier needed
    int q = lane >> 4, c = lane & 15;
    _Float16* sh = h1lds[wave];
    int k1 = lane, k2 = lane + 64;
    float w10 = W1[0 * 128 + k1], w11 = W1[1 * 128 + k1];
    float w12 = W1[2 * 128 + k1], w13 = W1[3 * 128 + k1], bb1 = b1[k1];
    float w20 = W1[0 * 128 + k2], w21 = W1[1 * 128 + k2];
    float w22 = W1[2 * 128 + k2], w23 = W1[3 * 128 + k2], bb2 = b1[k2];
    // B-fragments: lane holds W2[kt*32 + q*8 + j][nt*16 + c]
    f16x8 Bf[4][4];
#pragma unroll
    for (int kt = 0; kt < 4; kt++)
#pragma unroll
        for (int nt = 0; nt < 4; nt++)
#pragma unroll
            for (int j = 0; j < 8; j++)
                Bf[kt][nt][j] = (_Float16)W2[(kt * 32 + q * 8 + j) * 64 + nt * 16 + c];
    // Phase A: h1 from shagg
#pragma unroll
    for (int m = 0; m < 16; m++) {
        float4 a = *(const float4*)&shagg[wave][m * 4];
        float v1 = bb1, v2 = bb2;
        v1 = fmaf(a.x, w10, v1); v1 = fmaf(a.y, w11, v1);
        v1 = fmaf(a.z, w12, v1); v1 = fmaf(a.w, w13, v1);
        v2 = fmaf(a.x, w20, v2); v2 = fmaf(a.y, w21, v2);
        v2 = fmaf(a.z, w22, v2); v2 = fmaf(a.w, w23, v2);
        sh[m * HROW + k1] = (_Float16)fmaxf(v1, 0.f);
        sh[m * HROW + k2] = (_Float16)fmaxf(v2, 0.f);
    }
    // Phase B: 4 K-tiles x 4 N-tiles of 16x16x32 MFMA
    f32x4 C[4] = {{0.f, 0.f, 0.f, 0.f}, {0.f, 0.f, 0.f, 0.f},
                  {0.f, 0.f, 0.f, 0.f}, {0.f, 0.f, 0.f, 0.f}};
#pragma unroll
    for (int kt = 0; kt < 4; kt++) {
        f16x8 A = *(const f16x8*)&sh[c * HROW + kt * 32 + q * 8];
#pragma unroll
        for (int nt = 0; nt < 4; nt++)
            C[nt] = __builtin_amdgcn_mfma_f32_16x16x32_f16(A, Bf[kt][nt], C[nt], 0, 0, 0);
    }
#pragma unroll
    for (int nt = 0; nt < 4; nt++)
#pragma unroll
        for (int r = 0; r < 4; r++) {
            int node = base_n + q * 4 + r;                    // row = q*4 + reg
            if (node < N) y2h[(size_t)node * 64 + nt * 16 + c] = __float2half(C[nt][r]);
        }
}

// ---- layer 2 aggregation + bias/relu + W3 dot: 4 nodes x 2 slots x 8 octets
__global__ __launch_bounds__(256) void k_agg2(const __half* __restrict__ y2h,
                                              const int* __restrict__ cursor,
                                              const int2* __restrict__ payload,
                                              const float* __restrict__ b2,
                                              const float* __restrict__ W3,
                                              float* __restrict__ s_out) {
    int t = threadIdx.x, lane = t & 63, wave = t >> 6;
    int nsub = lane >> 4, slot = (lane >> 3) & 1, k = lane & 7;
    int n = (blockIdx.x * 4 + wave) * 4 + nsub;   // grid exact
    float b2v[8], w3v[8];
#pragma unroll
    for (int j = 0; j < 8; j++) { b2v[j] = b2[k * 8 + j]; w3v[j] = W3[k * 8 + j]; }
    int cnt = cursor[n];
    const int2* row = payload + (size_t)n * CAP;
    int iters = (cnt + 1) >> 1;
    float acc[8] = {0.f, 0.f, 0.f, 0.f, 0.f, 0.f, 0.f, 0.f};
    for (int it = 0; it < iters; it++) {
        int2 p = row[it * 2 + slot];
        float nm = __int_as_float(p.y);            // norm precomputed by k_l1
        f16x8 v = *(const f16x8*)(y2h + (size_t)p.x * 64 + k * 8);
#pragma unroll
        for (int j = 0; j < 8; j++)
            acc[j] = fmaf(nm, (float)v[j], acc[j]);
    }
#pragma unroll
    for (int j = 0; j < 8; j++) acc[j] += __shfl_xor(acc[j], 8);
    float p_ = 0.f;
#pragma unroll
    for (int j = 0; j < 8; j++) {
        float h = fmaxf(acc[j] + b2v[j], 0.f);
        p_ = fmaf(h, w3v[j], p_);
    }
    p_ += __shfl_xor(p_, 1);
    p_ += __shfl_xor(p_, 2);
    p_ += __shfl_xor(p_, 4);
    if (slot == 0 && k == 0) s_out[n] = p_;
}

// ---- layer 3 aggregation: 8 nodes x 8 slots per wave; out = acc + b3 -----
__global__ __launch_bounds__(256) void k_agg3(const float* __restrict__ s,
                                              const int* __restrict__ cursor,
                                              const int2* __restrict__ payload,
                                              const float* __restrict__ b3,
                                              float* __restrict__ out) {
    int t = threadIdx.x, lane = t & 63, wave = t >> 6;
    int nsub = lane >> 3, slot = lane & 7;
    int n = (blockIdx.x * 4 + wave) * 8 + nsub;   // grid exact
    int cnt = cursor[n];
    const int2* row = payload + (size_t)n * CAP;
    int iters = (cnt + 7) >> 3;
    float acc = 0.f;
    for (int it = 0; it < iters; it++) {
        int2 p = row[it * 8 + slot];
        acc = fmaf(__int_as_float(p.y), s[p.x], acc);  // pads: norm 0
    }
    acc += __shfl_xor(acc, 1);
    acc += __shfl_xor(acc, 2);
    acc += __shfl_xor(acc, 4);
    if (slot == 0) out[n] = acc + b3[0];
}

extern "C" void kernel_launch(void* const* d_in, const int* in_sizes, int n_in,
                              void* d_out, int out_size, void* d_ws, size_t ws_size,
                              hipStream_t stream) {
    const float* x  = (const float*)d_in[0];
    const int*   ei = (const int*)d_in[1];   // int32 (JAX x64-disabled)
    const int* src = ei;
    const int* dst = ei + E;
    const float* w  = (const float*)d_in[2];
    const float* W1 = (const float*)d_in[3];
    const float* b1 = (const float*)d_in[4];
    const float* W2 = (const float*)d_in[5];
    const float* b2 = (const float*)d_in[6];
    const float* W3 = (const float*)d_in[7];
    const float* b3 = (const float*)d_in[8];
    float* out = (float*)d_out;

    // layout: cursor[N] | dis[N] | s[N] | y2h[64N h] | cnt2d[GC*NBKT] |
    //         lofs2d[GC*NBKT] | stage[E int2] | payload[N*CAP int2]  (~72 MB)
    int*    cursor  = (int*)d_ws;
    float*  dis     = (float*)(cursor + N);
    float*  s       = dis + N;
    __half* y2h     = (__half*)(s + N);
    int*    cnt2d   = (int*)((char*)y2h + (size_t)64 * N * sizeof(__half));
    int*    lofs2d  = cnt2d + GC * NBKT;
    int2*   stage   = (int2*)(lofs2d + GC * NBKT);
    int2*   payload = stage + (size_t)GC * CHUNK;

    k_coarse<<<GC,           256, 0, stream>>>(src, dst, w, cnt2d, lofs2d, stage);
    k_fine  <<<NBKT,         512, 0, stream>>>(cnt2d, lofs2d, stage, payload, cursor, dis);
    k_l1    <<<cdiv(N, 64),  256, 0, stream>>>(x, dis, cursor, payload, W1, b1, W2, y2h);
    k_agg2  <<<N / 16,       256, 0, stream>>>(y2h, cursor, payload, b2, W3, s);
    k_agg3  <<<N / 32,       256, 0, stream>>>(s, cursor, payload, b3, out);
}

// Round 11
// 166.181 us; speedup vs baseline: 1.0212x; 1.0212x over previous
//
#include <hip/hip_runtime.h>
#include <hip/hip_fp16.h>

// GCN 3-layer, N=100000 nodes, E=800000 edges, f32.
// out = A_hat @ (relu(A_hat @ (relu((A_hat @ x) @ W1 + b1)) @ W2 + b2) @ W3) + b3
// A_hat = D^-1/2 (A + I) D^-1/2, weighted, deg over dst.
//
// R11 = R9 revert (R10's atomic-free build + agg1-fusion REGRESSED: binary
// search added dependent LDS chains; fusion cut gather occupancy 4x).
// R9 structure: LDS counting bucket sort (coarse: block-local sort + global
// range reservation + run-wise dump; fine: 512-thr per-bucket slotting),
// edge-parallel agg kernels with norm computed once (agg1) and written back,
// y2 fp16, layer-1 transform on MFMA. k_zero replaced by hipMemsetAsync.

constexpr int N = 100000;
constexpr int E = 800000;
constexpr int NBKT = 391;    // buckets of 256 nodes
constexpr int BCAP = 3072;   // per-bucket capacity; mean 2046, ~22 sigma margin
constexpr int GC = 125;      // coarse blocks; 125 * 6400 = E exactly
constexpr int CHUNK = 6400;  // 25 full 256-thread iterations

static inline int cdiv(int a, int b) { return (a + b - 1) / b; }

typedef __attribute__((ext_vector_type(8))) _Float16 f16x8;
typedef __attribute__((ext_vector_type(4))) float f32x4;

// coarse bucketing by dst>>8, block-local LDS counting sort, run-wise output.
// record = {src | (dst&255)<<17, bits(w)}
__global__ __launch_bounds__(256) void k_coarse(const int* __restrict__ src,
                                                const int* __restrict__ dst,
                                                const float* __restrict__ w,
                                                int* __restrict__ bucket_cursor,
                                                int2* __restrict__ sorted) {
    __shared__ int  hist[NBKT];     // per-bucket count, then kept for P5
    __shared__ int  lofs[512];      // scan workspace -> local exclusive offsets
    __shared__ int  gbase[NBKT];    // global base per bucket
    __shared__ int2 recs[CHUNK];    // 51.2 KB block-local sorted records
    int t = threadIdx.x;
    for (int i = t; i < NBKT; i += 256) hist[i] = 0;
    __syncthreads();
    int begin = blockIdx.x * CHUNK;
    int packed[25];                 // (rank<<17) | (bkt<<8) | dlo
#pragma unroll
    for (int i = 0; i < 25; i++) {
        int d = dst[begin + i * 256 + t];
        int b = d >> 8;
        int rank = atomicAdd(&hist[b], 1);
        packed[i] = (rank << 17) | (b << 8) | (d & 255);
    }
    __syncthreads();
    // P2: exclusive scan of hist[0..NBKT) via two independent 256-wide H-S scans
    int v0 = hist[t];
    int v1 = (256 + t < NBKT) ? hist[256 + t] : 0;
    lofs[t] = v0; lofs[256 + t] = v1;
    __syncthreads();
    for (int off = 1; off < 256; off <<= 1) {
        int u0 = (t >= off) ? lofs[t - off] : 0;
        int u1 = (t >= off) ? lofs[256 + t - off] : 0;
        __syncthreads();
        lofs[t] += u0; lofs[256 + t] += u1;
        __syncthreads();
    }
    int tot0 = lofs[255];
    lofs[t] -= v0;                       // inclusive -> exclusive
    lofs[256 + t] += tot0 - v1;
    __syncthreads();
    // P3: reserve global ranges (~391 atomics/block, 49k total)
    for (int i = t; i < NBKT; i += 256) {
        int h = hist[i];
        gbase[i] = h ? atomicAdd(&bucket_cursor[i], h) : 0;
    }
    __syncthreads();
    // P4: sort records into LDS (bucket-major)
#pragma unroll
    for (int i = 0; i < 25; i++) {
        int e = begin + i * 256 + t;
        int pk = packed[i];
        int b = (pk >> 8) & 511, rank = pk >> 17, dlo = pk & 255;
        recs[lofs[b] + rank] = make_int2(src[e] | (dlo << 17), __float_as_int(w[e]));
    }
    __syncthreads();
    // P5: per-bucket run copy — same-lane sequential 8B stores fill L2 lines
    for (int b = t; b < NBKT; b += 256) {
        int cnt = hist[b], lo = lofs[b], gb = gbase[b];
        int lim = BCAP - gb; if (cnt > lim) cnt = lim;
        int2* dstp = sorted + (size_t)b * BCAP + gb;
        for (int j = 0; j < cnt; j++) dstp[j] = recs[lo + j];
    }
}

// fine bucketing: one block per bucket, 512 threads. Slot 0 = self-loop {n,1.0};
// rows padded to x8 with {0, 0.0f}. Emits cursor/dis.
__global__ __launch_bounds__(512) void k_fine(const int2* __restrict__ sorted,
                                              const int* __restrict__ bucket_cursor,
                                              int cap, int2* __restrict__ payload,
                                              int* __restrict__ cursor,
                                              float* __restrict__ dis) {
    __shared__ int   ncnt[256];
    __shared__ float nwsum[256];
    int t = threadIdx.x, b = blockIdx.x;
    if (t < 256) { ncnt[t] = 1; nwsum[t] = 1.0f; }   // slot 0 = self-loop
    __syncthreads();
    int cnt = bucket_cursor[b]; if (cnt > BCAP) cnt = BCAP;
    const int2* seg = sorted + (size_t)b * BCAP;
    for (int i = t; i < cnt; i += 512) {
        int2 r = seg[i];
        int s = r.x & 0x1FFFF, dlo = r.x >> 17;
        int pos = atomicAdd(&ncnt[dlo], 1);
        atomicAdd(&nwsum[dlo], __int_as_float(r.y));
        if (pos < cap)
            payload[(size_t)(b * 256 + dlo) * cap + pos] = make_int2(s, r.y);
    }
    __syncthreads();
    int n = b * 256 + t;
    if (t < 256 && n < N) {
        int c = ncnt[t]; if (c > cap) c = cap;
        int2* row = payload + (size_t)n * cap;
        row[0] = make_int2(n, __float_as_int(1.0f));   // self-loop entry
        int cpad = (c + 7) & ~7;
        for (int e = c; e < cpad; e++) row[e] = make_int2(0, 0);
        cursor[n] = c;
        dis[n] = rsqrtf(nwsum[t]);
    }
}

// ---- layer 1 aggregation: 4 nodes x 4 edge-slots x 4 feats per wave ------
// Computes norm once per edge and writes it back into payload.y for agg2/agg3.
__global__ __launch_bounds__(256) void k_agg1(const float* __restrict__ x,
                                              const float* __restrict__ dis,
                                              const int* __restrict__ cursor,
                                              int2* __restrict__ payload, int cap,
                                              float* __restrict__ agg1) {
    int t = threadIdx.x, lane = t & 63, wave = t >> 6;
    int nsub = lane >> 4, slot = (lane >> 2) & 3, feat = lane & 3;
    int n = (blockIdx.x * 4 + wave) * 4 + nsub;   // grid exact: 6250*16 = N
    float di = dis[n];
    int cnt = cursor[n];
    int2* row = payload + (size_t)n * cap;
    int iters = (cnt + 3) >> 2;
    float acc = 0.f;
    for (int it = 0; it < iters; it++) {
        int e = it * 4 + slot;
        int2 p = row[e];
        float nm = dis[p.x] * __int_as_float(p.y) * di;  // self: di*1*di = di^2
        float xv = x[p.x * 4 + feat];
        acc = fmaf(nm, xv, acc);
        if (feat == 0) row[e].y = __float_as_int(nm);    // norm writeback
    }
    acc += __shfl_xor(acc, 4);
    acc += __shfl_xor(acc, 8);
    if (slot == 0) agg1[n * 4 + feat] = acc;
}

// ---- y2[n,:] = relu(agg1[n,:] @ W1 + b1) @ W2, fp16 out, via MFMA -------
constexpr int HROW = 136;  // f16 units per node row in LDS
__global__ __launch_bounds__(256) void k_fused_l1(const float4* __restrict__ agg1,
                                                  const float* __restrict__ W1,
                                                  const float* __restrict__ b1,
                                                  const float* __restrict__ W2,
                                                  __half* __restrict__ y2h) {
    __shared__ _Float16 h1lds[4][16 * HROW];   // 4 waves x 4352 B = 17408 B
    int t = threadIdx.x, wave = t >> 6, lane = t & 63;
    int q = lane >> 4, c = lane & 15;
    _Float16* sh = h1lds[wave];

    int k1 = lane, k2 = lane + 64;
    float w10 = W1[0 * 128 + k1], w11 = W1[1 * 128 + k1];
    float w12 = W1[2 * 128 + k1], w13 = W1[3 * 128 + k1], bb1 = b1[k1];
    float w20 = W1[0 * 128 + k2], w21 = W1[1 * 128 + k2];
    float w22 = W1[2 * 128 + k2], w23 = W1[3 * 128 + k2], bb2 = b1[k2];

    f16x8 Bf[4][4];
#pragma unroll
    for (int kt = 0; kt < 4; kt++)
#pragma unroll
        for (int nt = 0; nt < 4; nt++)
#pragma unroll
            for (int j = 0; j < 8; j++)
                Bf[kt][nt][j] = (_Float16)W2[(kt * 32 + q * 8 + j) * 64 + nt * 16 + c];

    int wave_id = blockIdx.x * 4 + wave;
#pragma unroll
    for (int g = 0; g < 2; g++) {
        int n0 = (wave_id * 2 + g) * 16;
        if (n0 >= N) break;
#pragma unroll
        for (int m = 0; m < 16; m++) {
            float4 a = agg1[n0 + m];
            float v1 = bb1, v2 = bb2;
            v1 = fmaf(a.x, w10, v1); v1 = fmaf(a.y, w11, v1);
            v1 = fmaf(a.z, w12, v1); v1 = fmaf(a.w, w13, v1);
            v2 = fmaf(a.x, w20, v2); v2 = fmaf(a.y, w21, v2);
            v2 = fmaf(a.z, w22, v2); v2 = fmaf(a.w, w23, v2);
            sh[m * HROW + k1] = (_Float16)fmaxf(v1, 0.f);
            sh[m * HROW + k2] = (_Float16)fmaxf(v2, 0.f);
        }
        f32x4 C[4] = {{0.f, 0.f, 0.f, 0.f}, {0.f, 0.f, 0.f, 0.f},
                      {0.f, 0.f, 0.f, 0.f}, {0.f, 0.f, 0.f, 0.f}};
#pragma unroll
        for (int kt = 0; kt < 4; kt++) {
            f16x8 A = *(const f16x8*)&sh[c * HROW + kt * 32 + q * 8];
#pragma unroll
            for (int nt = 0; nt < 4; nt++)
                C[nt] = __builtin_amdgcn_mfma_f32_16x16x32_f16(A, Bf[kt][nt], C[nt], 0, 0, 0);
        }
#pragma unroll
        for (int nt = 0; nt < 4; nt++)
#pragma unroll
            for (int r = 0; r < 4; r++) {
                int node = n0 + q * 4 + r;
                y2h[(size_t)node * 64 + nt * 16 + c] = __float2half(C[nt][r]);
            }
    }
}

// ---- layer 2 aggregation + bias/relu + W3 dot: 4 nodes x 2 slots x 8 octets
__global__ __launch_bounds__(256) void k_agg2(const __half* __restrict__ y2h,
                                              const int* __restrict__ cursor,
                                              const int2* __restrict__ payload, int cap,
                                              const float* __restrict__ b2,
                                              const float* __restrict__ W3,
                                              float* __restrict__ s_out) {
    int t = threadIdx.x, lane = t & 63, wave = t >> 6;
    int nsub = lane >> 4, slot = (lane >> 3) & 1, k = lane & 7;
    int n = (blockIdx.x * 4 + wave) * 4 + nsub;
    float b2v[8], w3v[8];
#pragma unroll
    for (int j = 0; j < 8; j++) { b2v[j] = b2[k * 8 + j]; w3v[j] = W3[k * 8 + j]; }
    int cnt = cursor[n];
    const int2* row = payload + (size_t)n * cap;
    int iters = (cnt + 1) >> 1;
    float acc[8] = {0.f, 0.f, 0.f, 0.f, 0.f, 0.f, 0.f, 0.f};
    for (int it = 0; it < iters; it++) {
        int2 p = row[it * 2 + slot];
        float nm = __int_as_float(p.y);            // norm precomputed by k_agg1
        f16x8 v = *(const f16x8*)(y2h + (size_t)p.x * 64 + k * 8);
#pragma unroll
        for (int j = 0; j < 8; j++)
            acc[j] = fmaf(nm, (float)v[j], acc[j]);
    }
#pragma unroll
    for (int j = 0; j < 8; j++) acc[j] += __shfl_xor(acc[j], 8);
    float p_ = 0.f;
#pragma unroll
    for (int j = 0; j < 8; j++) {
        float h = fmaxf(acc[j] + b2v[j], 0.f);
        p_ = fmaf(h, w3v[j], p_);
    }
    p_ += __shfl_xor(p_, 1);
    p_ += __shfl_xor(p_, 2);
    p_ += __shfl_xor(p_, 4);
    if (slot == 0 && k == 0) s_out[n] = p_;
}

// ---- layer 3 aggregation: 8 nodes x 8 slots per wave; out = acc + b3 -----
__global__ __launch_bounds__(256) void k_agg3(const float* __restrict__ s,
                                              const int* __restrict__ cursor,
                                              const int2* __restrict__ payload, int cap,
                                              const float* __restrict__ b3,
                                              float* __restrict__ out) {
    int t = threadIdx.x, lane = t & 63, wave = t >> 6;
    int nsub = lane >> 3, slot = lane & 7;
    int n = (blockIdx.x * 4 + wave) * 8 + nsub;
    int cnt = cursor[n];
    const int2* row = payload + (size_t)n * cap;
    int iters = (cnt + 7) >> 3;
    float acc = 0.f;
    for (int it = 0; it < iters; it++) {
        int2 p = row[it * 8 + slot];
        acc = fmaf(__int_as_float(p.y), s[p.x], acc);  // pads: norm 0
    }
    acc += __shfl_xor(acc, 1);
    acc += __shfl_xor(acc, 2);
    acc += __shfl_xor(acc, 4);
    if (slot == 0) out[n] = acc + b3[0];
}

extern "C" void kernel_launch(void* const* d_in, const int* in_sizes, int n_in,
                              void* d_out, int out_size, void* d_ws, size_t ws_size,
                              hipStream_t stream) {
    const float* x  = (const float*)d_in[0];
    const int*   ei = (const int*)d_in[1];   // int32 (JAX x64-disabled)
    const int* src = ei;
    const int* dst = ei + E;
    const float* w  = (const float*)d_in[2];
    const float* W1 = (const float*)d_in[3];
    const float* b1 = (const float*)d_in[4];
    const float* W2 = (const float*)d_in[5];
    const float* b2 = (const float*)d_in[6];
    const float* W3 = (const float*)d_in[7];
    const float* b3 = (const float*)d_in[8];
    float* out = (float*)d_out;

    // layout: bcur[512] | cursor[N] | dis[N] | agg1[4N] | y2h[64N h] |
    //         sorted[NBKT*BCAP int2] | payload[N*cap int2]
    int*    bcur    = (int*)d_ws;
    int*    cursor  = bcur + 512;
    float*  dis     = (float*)(cursor + N);
    float*  agg1    = dis + N;
    __half* y2h     = (__half*)(agg1 + 4 * N);
    float*  s       = agg1;                     // agg1 dead after k_fused_l1
    int2*   sorted  = (int2*)((char*)y2h + (size_t)64 * N * sizeof(__half));
    int2*   payload = sorted + (size_t)NBKT * BCAP;
    size_t fixed_bytes = (size_t)(512 + 2 * N + 4 * N) * 4 + (size_t)64 * N * 2
                       + (size_t)NBKT * BCAP * 8;
    int cap = (int)((ws_size - fixed_bytes) / ((size_t)N * 8));
    if (cap > 64) cap = 64;   // multiple of 8; Poisson(8)+self max << 64

    hipMemsetAsync(bcur, 0, NBKT * sizeof(int), stream);   // replaces k_zero
    k_coarse  <<<GC,              256, 0, stream>>>(src, dst, w, bcur, sorted);
    k_fine    <<<NBKT,            512, 0, stream>>>(sorted, bcur, cap, payload, cursor, dis);
    k_agg1    <<<N / 16,          256, 0, stream>>>(x, dis, cursor, payload, cap, agg1);
    k_fused_l1<<<cdiv(N / 16, 8), 256, 0, stream>>>((const float4*)agg1, W1, b1, W2, y2h);
    k_agg2    <<<N / 16,          256, 0, stream>>>(y2h, cursor, payload, cap, b2, W3, s);
    k_agg3    <<<N / 32,          256, 0, stream>>>(s, cursor, payload, cap, b3, out);
}